// Round 4
// baseline (8854.699 us; speedup 1.0000x reference)
//
#include <hip/hip_runtime.h>
#include <cstdint>
#include <cstddef>

#define NEGV -1000000000.0f
#define NBLK 512u

// ---------- fast device math (fp32, argmax-safe) ----------
__device__ __forceinline__ float fsigm(float x) {
  return 1.0f / (1.0f + __expf(-x));
}
__device__ __forceinline__ float ftanh(float x) {
  x = fminf(x, 30.0f);
  const float e = __expf(2.0f * x);
  return (e - 1.0f) / (e + 1.0f);
}

// ---------- grid barrier (epoch-based; persistent-kernel pattern) ----------
// Co-residency of all NBLK blocks is guaranteed by __launch_bounds__(256,2):
// <=256 VGPR + ~16.7KB LDS -> 2 blocks/CU x 256 CUs = 512 resident.
__device__ __forceinline__ void gsync(unsigned* cnt, unsigned* rel, unsigned epoch) {
  __syncthreads();
  if (threadIdx.x == 0) {
    __threadfence();   // device-scope release: flush h/xb writes across XCDs
    unsigned prev = __hip_atomic_fetch_add(cnt, 1u, __ATOMIC_ACQ_REL,
                                           __HIP_MEMORY_SCOPE_AGENT);
    if (prev == epoch * NBLK - 1u) {
      __hip_atomic_store(rel, epoch, __ATOMIC_RELEASE, __HIP_MEMORY_SCOPE_AGENT);
    } else {
      while (__hip_atomic_load(rel, __ATOMIC_ACQUIRE, __HIP_MEMORY_SCOPE_AGENT) < epoch)
        __builtin_amdgcn_s_sleep(1);
    }
  }
  __syncthreads();
}

// ---------------------------------------------------------------------------
// prep1: everything with no intra-launch dependencies.
// ---------------------------------------------------------------------------
__global__ __launch_bounds__(256) void prep1_k(
    const float* __restrict__ dec, const float* __restrict__ h0,
    const float* __restrict__ Wih, const float* __restrict__ Whh,
    const float* __restrict__ bih, const float* __restrict__ bhh,
    const float* __restrict__ Wqg, const float* __restrict__ Wm,
    const float* __restrict__ bm, const float* __restrict__ bqg,
    const float* __restrict__ Wqp, const float* __restrict__ Wrg,
    const float* __restrict__ brg, const float* __restrict__ bqp,
    float* __restrict__ xb, float* __restrict__ hb0,
    unsigned long long* __restrict__ maskb,
    float* __restrict__ Wcat, float* __restrict__ bcat,
    float* __restrict__ Wfused, float* __restrict__ bfused,
    float* __restrict__ Wgp, float* __restrict__ bgp,
    unsigned* __restrict__ bar)
{
  const int blk = blockIdx.x, t = threadIdx.x;
  if (blk == 0) {
    if (t < 2) bar[t] = 0u;
    float acc = bqp[t];
    for (int tt = 0; tt < 256; ++tt) acc += Wqp[(t << 8) + tt] * brg[tt];
    bgp[t] = acc;
  } else if (blk <= 512) {
    const int i = ((blk - 1) << 8) + t;
    xb[i] = dec[i]; hb0[i] = h0[i];
    if (i < 512) maskb[i] = 0ULL;
  } else if (blk <= 2560) {
    const int id = ((blk - 513) << 8) + t;
    const int n = id >> 9, k = id & 511;
    const int r = ((n & 3) << 8) + (n >> 2);
    Wcat[id] = (k < 256) ? Wih[(r << 8) + k] : Whh[(r << 8) + (k - 256)];
    if (id < 1024) {
      const int rr = ((id & 3) << 8) + (id >> 2);
      bcat[id] = bih[rr] + bhh[rr];
    }
  } else if (blk <= 2880) {
    const int id = ((blk - 2561) << 8) + t;   // 0..81919
    const int o = id / 320, j = id % 320;
    float acc = 0.f;
    for (int tt = 0; tt < 256; ++tt) acc += Wqg[(o << 8) + tt] * Wm[tt * 320 + j];
    Wfused[id] = acc;
    if (id < 256) {
      float a2 = 0.f;
      for (int tt = 0; tt < 256; ++tt) a2 += Wqg[(id << 8) + tt] * bm[tt];
      bfused[id] = a2 + bqg[id];
    }
  } else {
    const int o = blk - 2881, k = t;
    float acc = 0.f;
    for (int tt = 0; tt < 256; ++tt) acc += Wqp[(o << 8) + tt] * Wrg[(tt << 8) + k];
    Wgp[(o << 8) + k] = acc;
  }
}

// ---------------------------------------------------------------------------
// gemm256: C[m][n] = A[m][:256] @ W[n][:256]^T + bias[n]; M=32768, N=256.
// e-array layout [l][b][h] == context layout -> fully coalesced both sides.
// ---------------------------------------------------------------------------
__device__ __forceinline__ void gemm256(const float* __restrict__ A,
    const float* __restrict__ W, const float* __restrict__ bias,
    float* __restrict__ C, int bx, int by, int t)
{
  __shared__ __align__(16) float As[16][68];
  __shared__ __align__(16) float Ws2[16][68];
  const int bn = bx << 6, bm = by << 6;
  const int ty = t >> 4, tx = t & 15;
  const int lr = t >> 2, lk = (t & 3) << 2;
  const int m  = bm + lr;
  const float* wrow = W + ((size_t)(bn + lr) << 8);
  float acc[4][4] = {};
  for (int k0 = 0; k0 < 256; k0 += 16) {
    const int kk = k0 + lk;
    const float4 av = *(const float4*)(A + ((size_t)m << 8) + kk);
    const float4 wv = *(const float4*)(wrow + kk);
    As[lk + 0][lr] = av.x; As[lk + 1][lr] = av.y; As[lk + 2][lr] = av.z; As[lk + 3][lr] = av.w;
    Ws2[lk + 0][lr] = wv.x; Ws2[lk + 1][lr] = wv.y; Ws2[lk + 2][lr] = wv.z; Ws2[lk + 3][lr] = wv.w;
    __syncthreads();
#pragma unroll
    for (int k = 0; k < 16; ++k) {
      const float4 a4 = *(const float4*)&As[k][ty << 2];
      const float4 w4 = *(const float4*)&Ws2[k][tx << 2];
      acc[0][0] += a4.x * w4.x; acc[0][1] += a4.x * w4.y; acc[0][2] += a4.x * w4.z; acc[0][3] += a4.x * w4.w;
      acc[1][0] += a4.y * w4.x; acc[1][1] += a4.y * w4.y; acc[1][2] += a4.y * w4.z; acc[1][3] += a4.y * w4.w;
      acc[2][0] += a4.z * w4.x; acc[2][1] += a4.z * w4.y; acc[2][2] += a4.z * w4.z; acc[2][3] += a4.z * w4.w;
      acc[3][0] += a4.w * w4.x; acc[3][1] += a4.w * w4.y; acc[3][2] += a4.w * w4.z; acc[3][3] += a4.w * w4.w;
    }
    __syncthreads();
  }
  const float4 bv = *(const float4*)(bias + bn + (tx << 2));
#pragma unroll
  for (int i = 0; i < 4; ++i) {
    float4 o;
    o.x = acc[i][0] + bv.x; o.y = acc[i][1] + bv.y;
    o.z = acc[i][2] + bv.z; o.w = acc[i][3] + bv.w;
    *(float4*)(C + ((size_t)(bm + (ty << 2) + i) << 8) + bn + (tx << 2)) = o;
  }
}

// ---------------------------------------------------------------------------
// prep2: three 32768x256x256 GEMMs (e2g, e2p, Eg2) + Wq1T4 + qcour.
// ---------------------------------------------------------------------------
__global__ __launch_bounds__(256) void prep2_k(
    const float* __restrict__ ctxin,
    const float* __restrict__ Wrg, const float* __restrict__ brg,
    const float* __restrict__ Wrp, const float* __restrict__ brp,
    const float* __restrict__ Wgp, const float* __restrict__ bgp,
    const float* __restrict__ Wqg, const float* __restrict__ Wm,
    const float* __restrict__ Wfused, const float* __restrict__ bfused,
    const float* __restrict__ cour,
    float* __restrict__ e2g, float* __restrict__ e2p, float* __restrict__ Eg2,
    float* __restrict__ Wq1T4, float* __restrict__ qcour)
{
  const int blk = blockIdx.x, t = threadIdx.x;
  if (blk < 2048) {
    gemm256(ctxin, Wrg, brg, e2g, blk & 3, blk >> 2, t);
  } else if (blk < 4096) {
    const int b2 = blk - 2048;
    gemm256(ctxin, Wrp, brp, e2p, b2 & 3, b2 >> 2, t);
  } else if (blk < 6144) {
    const int b2 = blk - 4096;
    gemm256(ctxin, Wgp, bgp, Eg2, b2 & 3, b2 >> 2, t);
  } else if (blk < 6400) {
    const int o = blk - 6144;
    float acc = 0.f;
    for (int t2 = 0; t2 < 256; ++t2) acc += Wqg[(o << 8) + t2] * Wm[t2 * 320 + t];
    Wq1T4[((t >> 2) << 10) + (o << 2) + (t & 3)] = acc;
  } else {
    const int b = blk - 6400;
    __shared__ float cs[64];
    if (t < 64) cs[t] = cour[(b << 6) + t];
    __syncthreads();
    float acc = bfused[t];
#pragma unroll 8
    for (int k = 0; k < 64; ++k) acc += Wfused[t * 320 + 256 + k] * cs[k];
    qcour[(b << 8) + t] = acc;
  }
}

// ---------------------------------------------------------------------------
// Persistent kernel: all 64 steps, 2 grid barriers per step.
// Phase A: block = (16 gate-col block, 16 batch rows); c in 1 VGPR/thread.
// Phase B: block = one batch row.
// ---------------------------------------------------------------------------
struct CoopArgs {
  const float* c0; const float* emb;
  const float* Wcat; const float* bcat;
  const float* e2g; const float* e2p; const float* Eg2;
  const float* Wq1T4; const float* qcour;
  const float* vg; const float* vp;
  float* hb0; float* hb1; float* xb;
  unsigned long long* maskb; int* idxb;
  float* out_logp; float* out_sel;
  unsigned* cnt; unsigned* rel;
};

__global__ __launch_bounds__(256, 2) void decoder_loop_k(CoopArgs a)
{
  const int bid = blockIdx.x;
  const int t_  = threadIdx.x;

  // ---- phase-A geometry (fixed for all 64 steps) ----
  const int bnA = (bid & 15) << 6;          // gate-col block * 64
  const int bmA = (bid >> 4) << 4;          // batch-row block * 16
  const int tyA = t_ >> 4, txA = t_ & 15;
  const int jcA = (bnA >> 2) + txA;         // hidden unit owned by this thread
  const int mA  = bmA + tyA;                // batch row owned by this thread
  const int akA = (t_ & 15) << 1;
  const int arowA = bmA + (t_ >> 4);
  const int wrA = t_ >> 2, wkA = (t_ & 3) << 3;
  const float* wrowA = a.Wcat + ((size_t)(bnA + wrA) << 9);
  float c_reg = a.c0[(mA << 8) + jcA];      // LSTM cell state: 1 VGPR, 64 steps
  const float4 bregA = *(const float4*)(a.bcat + bnA + (txA << 2));

  // ---- phase-B geometry ----
  const int bB = bid;
  const int w = t_ >> 6, lane = t_ & 63;
  const float qcr = a.qcour[(bB << 8) + t_];

  __shared__ __align__(16) float As[16][36];
  __shared__ __align__(16) float Ws[32][68];
  __shared__ __align__(16) float hs[256], qgs[256], qps[256], vgs[256], vps[256];
  __shared__ float us[64], ps[64];
  __shared__ unsigned long long msh;
  __shared__ int bsel;

  vgs[t_] = a.vg[t_];
  vps[t_] = a.vp[t_];

  unsigned ep = 0;
  for (int t = 0; t < 64; ++t) {
    const float* hin = (t & 1) ? a.hb1 : a.hb0;
    float* hout      = (t & 1) ? a.hb0 : a.hb1;

    // ================= phase A: gates GEMM + LSTM pointwise =================
    {
      float acc0 = 0.f, acc1 = 0.f, acc2 = 0.f, acc3 = 0.f;
      for (int k0 = 0; k0 < 512; k0 += 32) {
        const int kk = k0 + akA;
        float2 av;
        if (kk < 256) av = *(const float2*)(a.xb + ((size_t)arowA << 8) + kk);
        else          av = *(const float2*)(hin  + ((size_t)arowA << 8) + (kk - 256));
        const float4 w0 = *(const float4*)(wrowA + k0 + wkA);
        const float4 w1 = *(const float4*)(wrowA + k0 + wkA + 4);
        *(float2*)&As[t_ >> 4][akA] = av;
        Ws[wkA + 0][wrA] = w0.x; Ws[wkA + 1][wrA] = w0.y;
        Ws[wkA + 2][wrA] = w0.z; Ws[wkA + 3][wrA] = w0.w;
        Ws[wkA + 4][wrA] = w1.x; Ws[wkA + 5][wrA] = w1.y;
        Ws[wkA + 6][wrA] = w1.z; Ws[wkA + 7][wrA] = w1.w;
        __syncthreads();
#pragma unroll
        for (int k = 0; k < 32; ++k) {
          const float av1 = As[tyA][k];
          const float4 wv = *(const float4*)&Ws[k][txA << 2];
          acc0 += av1 * wv.x; acc1 += av1 * wv.y;
          acc2 += av1 * wv.z; acc3 += av1 * wv.w;
        }
        __syncthreads();
      }
      const float ig = fsigm(acc0 + bregA.x);
      const float fg = fsigm(acc1 + bregA.y);
      const float gg = ftanh(acc2 + bregA.z);
      const float og = fsigm(acc3 + bregA.w);
      c_reg = fg * c_reg + ig * gg;
      hout[(mA << 8) + jcA] = og * ftanh(c_reg);
    }
    gsync(a.cnt, a.rel, ++ep);

    // ================= phase B: fused attention for batch row bB ============
    {
      hs[t_] = hout[(bB << 8) + t_];
      if (t_ == 0) {
        unsigned long long m = a.maskb[bB];
        if (t > 0) {
          int s = a.idxb[bB]; if (s < 0) s = 0;
          m |= (1ULL << s);
          if (m == ~0ULL) m &= ~(1ULL << 63);
          a.maskb[bB] = m;
        }
        msh = m;
      }
      __syncthreads();
      const unsigned long long mm = msh;

      // qg[t_] = qcour[bB,t_] + sum_k Wq1[t_][k] * h[bB,k]
      {
        float acc = qcr;
        const float4* wp = (const float4*)a.Wq1T4 + t_;
#pragma unroll 8
        for (int kc = 0; kc < 64; ++kc) {
          const float4 wv = wp[kc << 8];
          const float4 h4 = *(const float4*)&hs[kc << 2];
          acc += wv.x * h4.x + wv.y * h4.y + wv.z * h4.z + wv.w * h4.w;
        }
        qgs[t_] = acc;
      }
      __syncthreads();

      // scores_g over e2g[l][bB][:]
      {
        const float4 q4 = *(const float4*)&qgs[lane << 2];
        const float4 v4 = *(const float4*)&vgs[lane << 2];
        for (int li = 0; li < 16; ++li) {
          const int l = (w << 4) + li;
          const float4 e4 = *(const float4*)(a.e2g + ((size_t)l << 17) + (bB << 8) + (lane << 2));
          float s = v4.x * ftanh(q4.x + e4.x) + v4.y * ftanh(q4.y + e4.y)
                  + v4.z * ftanh(q4.z + e4.z) + v4.w * ftanh(q4.w + e4.w);
#pragma unroll
          for (int off = 32; off; off >>= 1) s += __shfl_xor(s, off, 64);
          if (lane == 0) us[l] = ((mm >> l) & 1ULL) ? NEGV : s;
        }
      }
      __syncthreads();
      if (t_ < 64) {
        const float xv = us[t_];
        float mx = xv;
#pragma unroll
        for (int off = 32; off; off >>= 1) mx = fmaxf(mx, __shfl_xor(mx, off, 64));
        const float ev = __expf(xv - mx);
        float sum = ev;
#pragma unroll
        for (int off = 32; off; off >>= 1) sum += __shfl_xor(sum, off, 64);
        ps[t_] = ev / sum;
      }
      __syncthreads();

      // qp[t_] = sum_l p[l] * Eg2[l][bB][t_]
      {
        float aq = 0.f;
        const float* ec = a.Eg2 + (bB << 8) + t_;
#pragma unroll 8
        for (int l = 0; l < 64; ++l) aq += ps[l] * ec[(size_t)l << 17];
        qps[t_] = aq;
      }
      __syncthreads();

      // scores_p over e2p[l][bB][:], 10*tanh, mask, log-softmax, argmax
      {
        const float4 q4 = *(const float4*)&qps[lane << 2];
        const float4 v4 = *(const float4*)&vps[lane << 2];
        for (int li = 0; li < 16; ++li) {
          const int l = (w << 4) + li;
          const float4 e4 = *(const float4*)(a.e2p + ((size_t)l << 17) + (bB << 8) + (lane << 2));
          float s = v4.x * ftanh(q4.x + e4.x) + v4.y * ftanh(q4.y + e4.y)
                  + v4.z * ftanh(q4.z + e4.z) + v4.w * ftanh(q4.w + e4.w);
#pragma unroll
          for (int off = 32; off; off >>= 1) s += __shfl_xor(s, off, 64);
          if (lane == 0) us[l] = ((mm >> l) & 1ULL) ? NEGV : 10.0f * ftanh(s);
        }
      }
      __syncthreads();
      if (t_ < 64) {
        const float xv = us[t_];
        float mx = xv;
#pragma unroll
        for (int off = 32; off; off >>= 1) mx = fmaxf(mx, __shfl_xor(mx, off, 64));
        const float sh = xv - mx;
        const float ev = __expf(sh);
        float sum = ev;
#pragma unroll
        for (int off = 32; off; off >>= 1) sum += __shfl_xor(sum, off, 64);
        const float lp = sh - __logf(sum);
        a.out_logp[((size_t)bB << 12) + (t << 6) + t_] = lp;
        float bv = lp; int bi = t_;
#pragma unroll
        for (int off = 32; off; off >>= 1) {
          const float ov = __shfl_xor(bv, off, 64);
          const int   oi = __shfl_xor(bi, off, 64);
          if (ov > bv || (ov == bv && oi < bi)) { bv = ov; bi = oi; }
        }
        if (t_ == 0) { a.idxb[bB] = bi; a.out_sel[(bB << 6) + t] = (float)bi; bsel = bi; }
      }
      __syncthreads();
      a.xb[(bB << 8) + t_] = a.emb[(((size_t)(bsel << 9) + bB) << 8) + t_];
    }
    gsync(a.cnt, a.rel, ++ep);
  }
}

// ---------------------------------------------------------------------------
extern "C" void kernel_launch(void* const* d_in, const int* in_sizes, int n_in,
                              void* d_out, int out_size, void* d_ws, size_t ws_size,
                              hipStream_t stream)
{
  const float* dec   = (const float*)d_in[0];
  const float* emb   = (const float*)d_in[1];
  const float* h0    = (const float*)d_in[2];
  const float* c0    = (const float*)d_in[3];
  const float* ctxin = (const float*)d_in[4];
  const float* cour  = (const float*)d_in[5];
  const float* Wih   = (const float*)d_in[7];
  const float* Whh   = (const float*)d_in[8];
  const float* bih   = (const float*)d_in[9];
  const float* bhh   = (const float*)d_in[10];
  const float* Wm    = (const float*)d_in[11];
  const float* bm    = (const float*)d_in[12];
  const float* Wqp   = (const float*)d_in[13];
  const float* bqp   = (const float*)d_in[14];
  const float* Wrp   = (const float*)d_in[15];
  const float* brp   = (const float*)d_in[16];
  const float* vp    = (const float*)d_in[17];
  const float* Wqg   = (const float*)d_in[18];
  const float* bqg   = (const float*)d_in[19];
  const float* Wrg   = (const float*)d_in[20];
  const float* brg   = (const float*)d_in[21];
  const float* vg    = (const float*)d_in[22];

  float* ws = (float*)d_ws;
  float* e2g    = ws + 0;         // [L][B][H] 8388608
  float* e2p    = ws + 8388608;   // 8388608
  float* Eg2    = ws + 16777216;  // 8388608
  float* Wcat   = ws + 25165824;  // 524288
  float* bcat   = ws + 25690112;  // 1024
  float* Wfused = ws + 25691136;  // 81920
  float* bfused = ws + 25773056;  // 256
  float* Wq1T4  = ws + 25773312;  // 65536
  float* qcour  = ws + 25838848;  // 131072
  float* Wgp    = ws + 25969920;  // 65536
  float* bgp    = ws + 26035456;  // 256
  float* hb0    = ws + 26035712;  // 131072
  float* hb1    = ws + 26166784;  // 131072
  float* xb     = ws + 26297856;  // 131072
  unsigned long long* maskb = (unsigned long long*)(ws + 26428928); // 512 u64
  int* idxb     = (int*)(ws + 26429952);                            // 512
  unsigned* bar = (unsigned*)(ws + 26430464);                       // cnt, rel

  float* out_logp = (float*)d_out;            // [B][64][64]
  float* out_sel  = (float*)d_out + 2097152;  // [B][64]

  prep1_k<<<3137, 256, 0, stream>>>(dec, h0, Wih, Whh, bih, bhh, Wqg, Wm, bm,
                                    bqg, Wqp, Wrg, brg, bqp,
                                    xb, hb0, maskb, Wcat, bcat, Wfused, bfused,
                                    Wgp, bgp, bar);
  prep2_k<<<6912, 256, 0, stream>>>(ctxin, Wrg, brg, Wrp, brp, Wgp, bgp,
                                    Wqg, Wm, Wfused, bfused, cour,
                                    e2g, e2p, Eg2, Wq1T4, qcour);

  CoopArgs ca;
  ca.c0 = c0; ca.emb = emb; ca.Wcat = Wcat; ca.bcat = bcat;
  ca.e2g = e2g; ca.e2p = e2p; ca.Eg2 = Eg2;
  ca.Wq1T4 = Wq1T4; ca.qcour = qcour; ca.vg = vg; ca.vp = vp;
  ca.hb0 = hb0; ca.hb1 = hb1; ca.xb = xb;
  ca.maskb = maskb; ca.idxb = idxb;
  ca.out_logp = out_logp; ca.out_sel = out_sel;
  ca.cnt = bar; ca.rel = bar + 1;
  decoder_loop_k<<<dim3(NBLK), dim3(256), 0, stream>>>(ca);
}

// Round 5
// 3876.176 us; speedup vs baseline: 2.2844x; 2.2844x over previous
//
#include <hip/hip_runtime.h>
#include <cstdint>
#include <cstddef>

#define NEGV -1000000000.0f

// ---------- fast device math (fp32, argmax-safe) ----------
__device__ __forceinline__ float fsigm(float x) { return 1.0f / (1.0f + __expf(-x)); }
__device__ __forceinline__ float ftanh(float x) {
  x = fminf(x, 30.0f);
  const float e = __expf(2.0f * x);
  return (e - 1.0f) / (e + 1.0f);
}

// ---------------------------------------------------------------------------
// prep1: weight repacks (no intra-launch deps).
//   blk 0        : bgp = Wqp@brg + bqp
//   blk 1..2048  : WcatT[k][n] (n=4j+p interleaved gates; k=[x|h]) + bcat
//   blk 2049..2368: Wfused = Wqg@Wm, bfused = Wqg@bm + bqg
//   blk 2369..2624: Wgp = Wqp@Wrg
// ---------------------------------------------------------------------------
__global__ __launch_bounds__(256) void prep1_k(
    const float* __restrict__ Wih, const float* __restrict__ Whh,
    const float* __restrict__ bih, const float* __restrict__ bhh,
    const float* __restrict__ Wqg, const float* __restrict__ Wm,
    const float* __restrict__ bm, const float* __restrict__ bqg,
    const float* __restrict__ Wqp, const float* __restrict__ Wrg,
    const float* __restrict__ brg, const float* __restrict__ bqp,
    float* __restrict__ WcatT, float* __restrict__ bcat,
    float* __restrict__ Wfused, float* __restrict__ bfused,
    float* __restrict__ Wgp, float* __restrict__ bgp)
{
  const int blk = blockIdx.x, t = threadIdx.x;
  if (blk == 0) {
    float acc = bqp[t];
    for (int tt = 0; tt < 256; ++tt) acc += Wqp[(t << 8) + tt] * brg[tt];
    bgp[t] = acc;
  } else if (blk <= 2048) {
    const int id = ((blk - 1) << 8) + t;      // 0..524287
    const int n = id & 1023, k = id >> 10;
    const int r = ((n & 3) << 8) + (n >> 2);  // source row of gate p, unit j
    WcatT[id] = (k < 256) ? Wih[(r << 8) + k] : Whh[(r << 8) + (k - 256)];
    if (id < 1024) {
      const int rr = ((id & 3) << 8) + (id >> 2);
      bcat[id] = bih[rr] + bhh[rr];
    }
  } else if (blk <= 2368) {
    const int id = ((blk - 2049) << 8) + t;   // 0..81919
    const int o = id / 320, j = id % 320;
    float acc = 0.f;
    for (int tt = 0; tt < 256; ++tt) acc += Wqg[(o << 8) + tt] * Wm[tt * 320 + j];
    Wfused[id] = acc;
    if (id < 256) {
      float a2 = 0.f;
      for (int tt = 0; tt < 256; ++tt) a2 += Wqg[(id << 8) + tt] * bm[tt];
      bfused[id] = a2 + bqg[id];
    }
  } else {
    const int o = blk - 2369, k = t;
    float acc = 0.f;
    for (int tt = 0; tt < 256; ++tt) acc += Wqp[(o << 8) + tt] * Wrg[(tt << 8) + k];
    Wgp[(o << 8) + k] = acc;
  }
}

// ---------------------------------------------------------------------------
// gemm256ct: A rows are physical context rows (m' = l*512+b) -> coalesced
// reads; stores go to e[b*64+l][:] (contiguous 1KB rows, permuted order).
// Same accumulation order as rounds 2-4 (BK=16 LDS tiles, k-sequential).
// ---------------------------------------------------------------------------
__device__ __forceinline__ void gemm256ct(const float* __restrict__ A,
    const float* __restrict__ W, const float* __restrict__ bias,
    float* __restrict__ C, int bx, int by, int t)
{
  __shared__ __align__(16) float As[16][68];
  __shared__ __align__(16) float Ws2[16][68];
  const int bn = bx << 6, bm = by << 6;
  const int ty = t >> 4, tx = t & 15;
  const int lr = t >> 2, lk = (t & 3) << 2;
  const int m  = bm + lr;
  const float* wrow = W + ((size_t)(bn + lr) << 8);
  float acc[4][4] = {};
  for (int k0 = 0; k0 < 256; k0 += 16) {
    const int kk = k0 + lk;
    const float4 av = *(const float4*)(A + ((size_t)m << 8) + kk);
    const float4 wv = *(const float4*)(wrow + kk);
    As[lk + 0][lr] = av.x; As[lk + 1][lr] = av.y; As[lk + 2][lr] = av.z; As[lk + 3][lr] = av.w;
    Ws2[lk + 0][lr] = wv.x; Ws2[lk + 1][lr] = wv.y; Ws2[lk + 2][lr] = wv.z; Ws2[lk + 3][lr] = wv.w;
    __syncthreads();
#pragma unroll
    for (int k = 0; k < 16; ++k) {
      const float4 a4 = *(const float4*)&As[k][ty << 2];
      const float4 w4 = *(const float4*)&Ws2[k][tx << 2];
      acc[0][0] += a4.x * w4.x; acc[0][1] += a4.x * w4.y; acc[0][2] += a4.x * w4.z; acc[0][3] += a4.x * w4.w;
      acc[1][0] += a4.y * w4.x; acc[1][1] += a4.y * w4.y; acc[1][2] += a4.y * w4.z; acc[1][3] += a4.y * w4.w;
      acc[2][0] += a4.z * w4.x; acc[2][1] += a4.z * w4.y; acc[2][2] += a4.z * w4.z; acc[2][3] += a4.z * w4.w;
      acc[3][0] += a4.w * w4.x; acc[3][1] += a4.w * w4.y; acc[3][2] += a4.w * w4.z; acc[3][3] += a4.w * w4.w;
    }
    __syncthreads();
  }
  const float4 bv = *(const float4*)(bias + bn + (tx << 2));
#pragma unroll
  for (int i = 0; i < 4; ++i) {
    const int rr = bm + (ty << 2) + i;        // physical row m' = l*512+b
    const int l = rr >> 9, b = rr & 511;
    float4 o;
    o.x = acc[i][0] + bv.x; o.y = acc[i][1] + bv.y;
    o.z = acc[i][2] + bv.z; o.w = acc[i][3] + bv.w;
    *(float4*)(C + (((size_t)(b << 6) + l) << 8) + bn + (tx << 2)) = o;
  }
}

// ---------------------------------------------------------------------------
// prep2: three 32768x256x256 GEMMs (e2g, e2p, Eg2 in [b][l][h]) + Wq1T4 + qcour
// ---------------------------------------------------------------------------
__global__ __launch_bounds__(256) void prep2_k(
    const float* __restrict__ ctxin,
    const float* __restrict__ Wrg, const float* __restrict__ brg,
    const float* __restrict__ Wrp, const float* __restrict__ brp,
    const float* __restrict__ Wgp, const float* __restrict__ bgp,
    const float* __restrict__ Wqg, const float* __restrict__ Wm,
    const float* __restrict__ Wfused, const float* __restrict__ bfused,
    const float* __restrict__ cour,
    float* __restrict__ e2g, float* __restrict__ e2p, float* __restrict__ Eg2,
    float* __restrict__ Wq1T4, float* __restrict__ qcour)
{
  const int blk = blockIdx.x, t = threadIdx.x;
  if (blk < 2048) {
    gemm256ct(ctxin, Wrg, brg, e2g, blk & 3, blk >> 2, t);
  } else if (blk < 4096) {
    const int b2 = blk - 2048;
    gemm256ct(ctxin, Wrp, brp, e2p, b2 & 3, b2 >> 2, t);
  } else if (blk < 6144) {
    const int b2 = blk - 4096;
    gemm256ct(ctxin, Wgp, bgp, Eg2, b2 & 3, b2 >> 2, t);
  } else if (blk < 6400) {
    const int o = blk - 6144;
    float acc = 0.f;
    for (int t2 = 0; t2 < 256; ++t2) acc += Wqg[(o << 8) + t2] * Wm[t2 * 320 + t];
    Wq1T4[((t >> 2) << 10) + (o << 2) + (t & 3)] = acc;
  } else {
    const int b = blk - 6400;
    __shared__ float cs[64];
    if (t < 64) cs[t] = cour[(b << 6) + t];
    __syncthreads();
    float acc = bfused[t];
#pragma unroll 8
    for (int k = 0; k < 64; ++k) acc += Wfused[t * 320 + 256 + k] * cs[k];
    qcour[(b << 8) + t] = acc;
  }
}

// ---------------------------------------------------------------------------
// Barrier-free persistent decoder: 256 blocks x 1024 threads; block owns
// batch rows (2*bid, 2*bid+1) end-to-end for all 64 steps. All recurrent
// state (x, h, c, mask, sel) lives in LDS/registers; only weights/e-arrays
// are streamed (L2/L3-resident). No atomics, no fences, no grid barrier.
// ---------------------------------------------------------------------------
__global__ __launch_bounds__(1024, 4) void decoder_loop_k(
    const float* __restrict__ dec, const float* __restrict__ h0,
    const float* __restrict__ c0, const float* __restrict__ emb,
    const float* __restrict__ WcatT, const float* __restrict__ bcat,
    const float* __restrict__ e2g, const float* __restrict__ e2p,
    const float* __restrict__ Eg2, const float* __restrict__ Wq1T4,
    const float* __restrict__ qcour, const float* __restrict__ vg,
    const float* __restrict__ vp, float* __restrict__ out_logp,
    float* __restrict__ out_sel)
{
  const int t_ = threadIdx.x;
  const int bid = blockIdx.x;
  const int b0 = bid << 1;
  const int tc = t_ & 255, tk = t_ >> 8;     // phase-A: 256 units x 4 K-chunks
  const int wv = t_ >> 6, lane = t_ & 63;

  __shared__ __align__(16) float xhs[2][512];     // [row][ x(256) | h(256) ]
  __shared__ __align__(16) float qcs[2][256];
  __shared__ __align__(16) float bcs[1024];
  __shared__ __align__(16) float vgs[256], vps[256];
  __shared__ __align__(16) float qgs[2][256], qps[2][256];
  __shared__ float us[2][64], ps[2][64];
  __shared__ __align__(16) float red[8][256][4];  // [(tk<<1)|row][unit][gate]
  __shared__ unsigned long long mlds[2];
  __shared__ int selLds[2];

  // ---- init: load all per-block state ----
  if (t_ < 512) {
    const int r = t_ >> 8, i = t_ & 255;
    xhs[r][i]       = dec[((b0 + r) << 8) + i];
    xhs[r][256 + i] = h0[((b0 + r) << 8) + i];
    qcs[r][i]       = qcour[((b0 + r) << 8) + i];
  } else if (t_ < 768) {
    vgs[t_ & 255] = vg[t_ & 255];
  } else {
    vps[t_ & 255] = vp[t_ & 255];
  }
  bcs[t_] = bcat[t_];
  float c_r0 = 0.f, c_r1 = 0.f;
  if (t_ < 256) {
    c_r0 = c0[(b0 << 8) + t_];
    c_r1 = c0[((b0 + 1) << 8) + t_];
  }
  if (t_ == 0) { mlds[0] = 0ULL; mlds[1] = 0ULL; selLds[0] = 0; selLds[1] = 0; }
  __syncthreads();

  const float* wbase = WcatT + ((size_t)tk << 17) + (tc << 2);
  const float* xh0 = &xhs[0][tk << 7];
  const float* xh1 = &xhs[1][tk << 7];

  for (int t = 0; t < 64; ++t) {
    // ---- mask update from previous selection (in-LDS, reference semantics) --
    if (t > 0 && t_ < 2) {
      unsigned long long m = mlds[t_];
      int s = selLds[t_]; if (s < 0) s = 0;
      m |= (1ULL << s);
      if (m == ~0ULL) m &= ~(1ULL << 63);
      mlds[t_] = m;
    }

    // ================= phase A: gates GEMM (K split 4-way) + LSTM ===========
    {
      float a00 = 0.f, a01 = 0.f, a02 = 0.f, a03 = 0.f;
      float a10 = 0.f, a11 = 0.f, a12 = 0.f, a13 = 0.f;
#pragma unroll 4
      for (int kk = 0; kk < 128; kk += 2) {
        const float2 x0 = *(const float2*)(xh0 + kk);
        const float2 x1 = *(const float2*)(xh1 + kk);
        const float4 w0 = *(const float4*)(wbase + ((size_t)kk << 10));
        const float4 w1 = *(const float4*)(wbase + ((size_t)(kk + 1) << 10));
        a00 += w0.x * x0.x; a01 += w0.y * x0.x; a02 += w0.z * x0.x; a03 += w0.w * x0.x;
        a10 += w0.x * x1.x; a11 += w0.y * x1.x; a12 += w0.z * x1.x; a13 += w0.w * x1.x;
        a00 += w1.x * x0.y; a01 += w1.y * x0.y; a02 += w1.z * x0.y; a03 += w1.w * x0.y;
        a10 += w1.x * x1.y; a11 += w1.y * x1.y; a12 += w1.z * x1.y; a13 += w1.w * x1.y;
      }
      *(float4*)&red[(tk << 1) | 0][tc][0] = make_float4(a00, a01, a02, a03);
      *(float4*)&red[(tk << 1) | 1][tc][0] = make_float4(a10, a11, a12, a13);
    }
    __syncthreads();
    if (t_ < 256) {
      const float4 b4 = *(const float4*)&bcs[t_ << 2];
      const float4 p0 = *(const float4*)&red[0][t_][0];
      const float4 p2 = *(const float4*)&red[2][t_][0];
      const float4 p4 = *(const float4*)&red[4][t_][0];
      const float4 p6 = *(const float4*)&red[6][t_][0];
      {
        const float gi = ((p0.x + p2.x) + p4.x) + p6.x + b4.x;
        const float gf = ((p0.y + p2.y) + p4.y) + p6.y + b4.y;
        const float gg = ((p0.z + p2.z) + p4.z) + p6.z + b4.z;
        const float go = ((p0.w + p2.w) + p4.w) + p6.w + b4.w;
        c_r0 = fsigm(gf) * c_r0 + fsigm(gi) * ftanh(gg);
        xhs[0][256 + t_] = fsigm(go) * ftanh(c_r0);
      }
      const float4 p1 = *(const float4*)&red[1][t_][0];
      const float4 p3 = *(const float4*)&red[3][t_][0];
      const float4 p5 = *(const float4*)&red[5][t_][0];
      const float4 p7 = *(const float4*)&red[7][t_][0];
      {
        const float gi = ((p1.x + p3.x) + p5.x) + p7.x + b4.x;
        const float gf = ((p1.y + p3.y) + p5.y) + p7.y + b4.y;
        const float gg = ((p1.z + p3.z) + p5.z) + p7.z + b4.z;
        const float go = ((p1.w + p3.w) + p5.w) + p7.w + b4.w;
        c_r1 = fsigm(gf) * c_r1 + fsigm(gi) * ftanh(gg);
        xhs[1][256 + t_] = fsigm(go) * ftanh(c_r1);
      }
    }
    __syncthreads();

    // ================= qg matvec: qg[r][o] = qcour + Wq1 @ h[r] =============
    if (t_ < 256) {
      float q0 = qcs[0][t_], q1 = qcs[1][t_];
      const float4* wp = (const float4*)Wq1T4 + t_;
#pragma unroll 8
      for (int kc = 0; kc < 64; ++kc) {
        const float4 w4  = wp[kc << 8];
        const float4 h40 = *(const float4*)&xhs[0][256 + (kc << 2)];
        const float4 h41 = *(const float4*)&xhs[1][256 + (kc << 2)];
        q0 += w4.x * h40.x + w4.y * h40.y + w4.z * h40.z + w4.w * h40.w;
        q1 += w4.x * h41.x + w4.y * h41.y + w4.z * h41.z + w4.w * h41.w;
      }
      qgs[0][t_] = q0; qgs[1][t_] = q1;
    }
    __syncthreads();

    // ================= scores_g: 16 waves x 8 (row,l) dots ==================
    {
      const int row = wv >> 3;
      const int lbase = (wv & 7) << 3;
      const float4 q4 = *(const float4*)&qgs[row][lane << 2];
      const float4 v4 = *(const float4*)&vgs[lane << 2];
      const float* eb = e2g + ((size_t)(b0 + row) << 14);
      for (int li = 0; li < 8; ++li) {
        const int l = lbase + li;
        const float4 e4 = *(const float4*)(eb + (l << 8) + (lane << 2));
        float s = v4.x * ftanh(q4.x + e4.x) + v4.y * ftanh(q4.y + e4.y)
                + v4.z * ftanh(q4.z + e4.z) + v4.w * ftanh(q4.w + e4.w);
#pragma unroll
        for (int off = 32; off; off >>= 1) s += __shfl_xor(s, off, 64);
        if (lane == 0) us[row][l] = ((mlds[row] >> l) & 1ULL) ? NEGV : s;
      }
    }
    __syncthreads();
    if (t_ < 128) {
      const int row = t_ >> 6;
      const float xv = us[row][lane];
      float mx = xv;
#pragma unroll
      for (int off = 32; off; off >>= 1) mx = fmaxf(mx, __shfl_xor(mx, off, 64));
      const float ev = __expf(xv - mx);
      float sum = ev;
#pragma unroll
      for (int off = 32; off; off >>= 1) sum += __shfl_xor(sum, off, 64);
      ps[row][lane] = ev / sum;
    }
    __syncthreads();

    // ================= qp[r][o] = sum_l ps[r][l] * Eg2[b_r][l][o] ===========
    if (t_ < 512) {
      const int r = t_ >> 8, o = t_ & 255;
      const float* ec = Eg2 + ((size_t)(b0 + r) << 14) + o;
      float aq = 0.f;
#pragma unroll 8
      for (int l = 0; l < 64; ++l) aq += ps[r][l] * ec[l << 8];
      qps[r][o] = aq;
    }
    __syncthreads();

    // ================= scores_p + 10*tanh + mask ============================
    {
      const int row = wv >> 3;
      const int lbase = (wv & 7) << 3;
      const float4 q4 = *(const float4*)&qps[row][lane << 2];
      const float4 v4 = *(const float4*)&vps[lane << 2];
      const float* eb = e2p + ((size_t)(b0 + row) << 14);
      for (int li = 0; li < 8; ++li) {
        const int l = lbase + li;
        const float4 e4 = *(const float4*)(eb + (l << 8) + (lane << 2));
        float s = v4.x * ftanh(q4.x + e4.x) + v4.y * ftanh(q4.y + e4.y)
                + v4.z * ftanh(q4.z + e4.z) + v4.w * ftanh(q4.w + e4.w);
#pragma unroll
        for (int off = 32; off; off >>= 1) s += __shfl_xor(s, off, 64);
        if (lane == 0) us[row][l] = ((mlds[row] >> l) & 1ULL) ? NEGV : 10.0f * ftanh(s);
      }
    }
    __syncthreads();

    // ================= log-softmax, argmax, outputs =========================
    if (t_ < 128) {
      const int row = t_ >> 6;
      const float xv = us[row][lane];
      float mx = xv;
#pragma unroll
      for (int off = 32; off; off >>= 1) mx = fmaxf(mx, __shfl_xor(mx, off, 64));
      const float sh = xv - mx;
      const float ev = __expf(sh);
      float sum = ev;
#pragma unroll
      for (int off = 32; off; off >>= 1) sum += __shfl_xor(sum, off, 64);
      const float lp = sh - __logf(sum);
      out_logp[((size_t)(b0 + row) << 12) + (t << 6) + lane] = lp;
      float bv = lp; int bi = lane;
#pragma unroll
      for (int off = 32; off; off >>= 1) {
        const float ov = __shfl_xor(bv, off, 64);
        const int   oi = __shfl_xor(bi, off, 64);
        if (ov > bv || (ov == bv && oi < bi)) { bv = ov; bi = oi; }
      }
      if (lane == 0) {
        selLds[row] = bi;
        out_sel[((b0 + row) << 6) + t] = (float)bi;
      }
    }
    __syncthreads();

    // ================= embedding gather -> next x ===========================
    if (t_ < 512) {
      const int r = t_ >> 8, o = t_ & 255;
      xhs[r][o] = emb[(((size_t)(selLds[r] << 9) + b0 + r) << 8) + o];
    }
    __syncthreads();
  }
}

// ---------------------------------------------------------------------------
extern "C" void kernel_launch(void* const* d_in, const int* in_sizes, int n_in,
                              void* d_out, int out_size, void* d_ws, size_t ws_size,
                              hipStream_t stream)
{
  const float* dec   = (const float*)d_in[0];
  const float* emb   = (const float*)d_in[1];
  const float* h0    = (const float*)d_in[2];
  const float* c0    = (const float*)d_in[3];
  const float* ctxin = (const float*)d_in[4];
  const float* cour  = (const float*)d_in[5];
  const float* Wih   = (const float*)d_in[7];
  const float* Whh   = (const float*)d_in[8];
  const float* bih   = (const float*)d_in[9];
  const float* bhh   = (const float*)d_in[10];
  const float* Wm    = (const float*)d_in[11];
  const float* bm    = (const float*)d_in[12];
  const float* Wqp   = (const float*)d_in[13];
  const float* bqp   = (const float*)d_in[14];
  const float* Wrp   = (const float*)d_in[15];
  const float* brp   = (const float*)d_in[16];
  const float* vp    = (const float*)d_in[17];
  const float* Wqg   = (const float*)d_in[18];
  const float* bqg   = (const float*)d_in[19];
  const float* Wrg   = (const float*)d_in[20];
  const float* brg   = (const float*)d_in[21];
  const float* vg    = (const float*)d_in[22];

  float* ws = (float*)d_ws;
  float* e2g    = ws + 0;         // [B][L][H] 8388608
  float* e2p    = ws + 8388608;   // 8388608
  float* Eg2    = ws + 16777216;  // 8388608
  float* WcatT  = ws + 25165824;  // [K=512][N=1024] 524288
  float* bcat   = ws + 25690112;  // 1024
  float* Wfused = ws + 25691136;  // 81920
  float* bfused = ws + 25773056;  // 256
  float* Wq1T4  = ws + 25773312;  // 65536
  float* qcour  = ws + 25838848;  // 131072
  float* Wgp    = ws + 25969920;  // 65536
  float* bgp    = ws + 26035456;  // 256

  float* out_logp = (float*)d_out;            // [B][64][64]
  float* out_sel  = (float*)d_out + 2097152;  // [B][64]

  prep1_k<<<2625, 256, 0, stream>>>(Wih, Whh, bih, bhh, Wqg, Wm, bm, bqg,
                                    Wqp, Wrg, brg, bqp,
                                    WcatT, bcat, Wfused, bfused, Wgp, bgp);
  prep2_k<<<6912, 256, 0, stream>>>(ctxin, Wrg, brg, Wrp, brp, Wgp, bgp,
                                    Wqg, Wm, Wfused, bfused, cour,
                                    e2g, e2p, Eg2, Wq1T4, qcour);
  decoder_loop_k<<<256, 1024, 0, stream>>>(dec, h0, c0, emb, WcatT, bcat,
                                           e2g, e2p, Eg2, Wq1T4, qcour,
                                           vg, vp, out_logp, out_sel);
}